// Round 3
// baseline (93.005 us; speedup 1.0000x reference)
//
#include <hip/hip_runtime.h>

#define SCALE 0.35355339059327379f   // 8^-0.5
#define RSQRT2 0.70710678118654752f

// ws layout (float offsets)
#define QT_SZ   (68*68*64)           // padded transposed q image: [xp][yp][ic]
#define WT_SZ   (64*121*64)          // [oc][kh*11+kw][ic]
#define QT_OFF  0
#define KT_OFF  (QT_OFF + QT_SZ)
#define WQT_OFF (KT_OFF + QT_SZ)
#define WKT_OFF (WQT_OFF + WT_SZ)
#define QD_OFF  (WKT_OFF + WT_SZ)    // [oc][il] 64*64
#define KD_OFF  (QD_OFF + 4096)
#define VP_OFF  (KD_OFF + 4096)      // Vpart [yg][x][ch] 8*64*64
#define CNT_OFF (VP_OFF + 8*64*64)   // atomic release counter (1 u32)

// ---------------- K1: 1x1 conv (q,k -> transposed padded imgs; v -> row-mean partials)
//                  + weight transposes for K2 + counter zeroing ----------------
__global__ __launch_bounds__(192) void k1(const float* __restrict__ f,
                                          const float* __restrict__ w_qkv,
                                          const float* __restrict__ wq,
                                          const float* __restrict__ wk,
                                          float* __restrict__ ws)
{
    extern __shared__ float sm[];
    const int b = blockIdx.x, t = threadIdx.x;
    if (b == 0 && t == 0) *(unsigned*)(ws + CNT_OFF) = 0u;   // visible to K2 via kernel boundary
    if (b < 512) {
        // compute block: x row, yg = group of 8 y's
        const int x = b >> 3, yg = b & 7;
        const int w = t >> 6, lane = t & 63;   // wave w: 0=q,1=k,2=v ; lane = oc
        float* fl = sm;           // [64][12] f slab (8 y per ic, padded pitch 12)
        float* wt = sm + 768;     // [64 ic][193] transposed w_qkv (pitch 193)
        if (t < 128) {
            const int ic = t >> 1, part = t & 1;
            *(float4*)&fl[ic*12 + part*4] =
                *(const float4*)(f + ic*4096 + x*64 + yg*8 + part*4);
        }
        #pragma unroll
        for (int j = 0; j < 16; ++j) {
            const int idx = t + 192*j;          // float4 index in [0,3072)
            float4 v = *(const float4*)(w_qkv + 4*idx);
            const int oc = idx >> 4;            // (4*idx)/64
            const int ic0 = (4*idx) & 63;
            wt[(ic0+0)*193 + oc] = v.x;
            wt[(ic0+1)*193 + oc] = v.y;
            wt[(ic0+2)*193 + oc] = v.z;
            wt[(ic0+3)*193 + oc] = v.w;
        }
        __syncthreads();
        float acc[8] = {0.f,0.f,0.f,0.f,0.f,0.f,0.f,0.f};
        #pragma unroll 8
        for (int ic = 0; ic < 64; ++ic) {
            const float wv = wt[ic*193 + w*64 + lane];
            const float4 a = *(const float4*)&fl[ic*12];
            const float4 c = *(const float4*)&fl[ic*12 + 4];
            acc[0] = fmaf(wv, a.x, acc[0]);
            acc[1] = fmaf(wv, a.y, acc[1]);
            acc[2] = fmaf(wv, a.z, acc[2]);
            acc[3] = fmaf(wv, a.w, acc[3]);
            acc[4] = fmaf(wv, c.x, acc[4]);
            acc[5] = fmaf(wv, c.y, acc[5]);
            acc[6] = fmaf(wv, c.z, acc[6]);
            acc[7] = fmaf(wv, c.w, acc[7]);
        }
        if (w < 2) {
            float* img = (w == 0) ? (ws + QT_OFF) : (ws + KT_OFF);
            const int rowb = (x + 2) * 68;
            #pragma unroll
            for (int j = 0; j < 8; ++j)
                img[(rowb + yg*8 + j + 2)*64 + lane] = acc[j];
            if (yg == 0) { img[(rowb+0)*64+lane] = 0.f; img[(rowb+1)*64+lane] = 0.f; }
            if (yg == 7) { img[(rowb+66)*64+lane] = 0.f; img[(rowb+67)*64+lane] = 0.f; }
            if (x < 4) {  // zero pad rows xp in {0,1,66,67}; yg splits the 68 cols
                const int xp = (x < 2) ? x : 64 + x;
                for (int yp = yg*9; yp < yg*9 + 9; ++yp)
                    if (yp < 68) img[(xp*68 + yp)*64 + lane] = 0.f;
            }
        } else {
            const float s = acc[0]+acc[1]+acc[2]+acc[3]+acc[4]+acc[5]+acc[6]+acc[7];
            (ws + VP_OFF)[(yg*64 + x)*64 + lane] = s * 0.015625f;   // /64 row-mean partial
        }
    } else {
        // weight transpose blocks: wq/wk [oc][ic][kh][kw] -> [oc][kh*11+kw][ic]
        const int b2 = b - 512;
        const int type = b2 >> 6, oc = b2 & 63;
        const float* wsrc = type ? wk : wq;
        float* wdst = type ? (ws + WKT_OFF) : (ws + WQT_OFF);
        float* wl = sm;   // 7744 floats, [ic][121]
        #pragma unroll
        for (int j = 0; j < 11; ++j) {
            const int idx = t + 192*j;
            if (idx < 1936)
                *(float4*)&wl[4*idx] = *(const float4*)(wsrc + oc*7744 + 4*idx);
        }
        __syncthreads();
        const int w = t >> 6, lane = t & 63;
        for (int j = 0; j < 41; ++j) {
            const int k = w + 3*j;
            if (k < 121)
                wdst[(oc*121 + k)*64 + lane] = wl[lane*121 + k];
        }
    }
}

// ---------------- K2: fused {11x11 s8 conv + GELU} (blocks 0..255)
//                  and {attention epilogue} (spinner blocks 256..319) ----------------
__global__ __launch_bounds__(256) void k2(const float* __restrict__ ws_qT,
                                          const float* __restrict__ ws_kT,
                                          const float* __restrict__ ws_wqT,
                                          const float* __restrict__ ws_wkT,
                                          const float* __restrict__ bq,
                                          const float* __restrict__ bk,
                                          float* qd, float* kd,
                                          const float* __restrict__ Vpart,
                                          unsigned* cnt,
                                          float* __restrict__ out)
{
    __shared__ float patch[64*223];   // conv: [64 ic][223]; spinners reuse as vrow[64][65]
    const int b = blockIdx.x;
    const int t = threadIdx.x;

    if (b < 256) {
        // ---- conv block ----
        const int type = b >> 7, ox = (b >> 4) & 7, ocg = (b >> 1) & 7, oyh = b & 1;
        const float* img  = type ? ws_kT : ws_qT;
        const float* wT   = type ? ws_wkT : ws_wqT;
        const float* bias = type ? bk : bq;
        float* outp = type ? kd : qd;
        const int ocp = t >> 6, lane = t & 63;

        const int oc0 = ocg*8 + ocp*2, oc1 = oc0 + 1;
        const float* wb0 = wT + oc0*121*64 + lane;
        const float* wb1 = wT + oc1*121*64 + lane;
        float acc0[4] = {0.f,0.f,0.f,0.f};
        float acc1[4] = {0.f,0.f,0.f,0.f};

        #pragma unroll
        for (int chunk = 0; chunk < 2; ++chunk) {
            const int kh0 = chunk ? 6 : 0;
            const int nkh = chunk ? 5 : 6;
            if (chunk) __syncthreads();
            for (int kh = 0; kh < nkh; ++kh) {
                const int xrow = (ox*8 + kh0 + kh) * 68;
                for (int yl = ocp; yl < 35; yl += 4)
                    patch[lane*223 + kh*37 + yl] = img[(xrow + oyh*32 + yl)*64 + lane];
            }
            __syncthreads();
            for (int kh = 0; kh < nkh; ++kh) {
                const float* prow = &patch[lane*223 + kh*37];
                const int khg = kh0 + kh;
                #pragma unroll
                for (int kw = 0; kw < 11; ++kw) {
                    const float w0 = wb0[(khg*11 + kw)*64];
                    const float w1 = wb1[(khg*11 + kw)*64];
                    #pragma unroll
                    for (int oy = 0; oy < 4; ++oy) {
                        const float v = prow[kw + oy*8];
                        acc0[oy] = fmaf(w0, v, acc0[oy]);
                        acc1[oy] = fmaf(w1, v, acc1[oy]);
                    }
                }
            }
        }

        #pragma unroll
        for (int j = 0; j < 4; ++j) {
            float v0 = acc0[j], v1 = acc1[j];
            #pragma unroll
            for (int m = 1; m < 64; m <<= 1) {
                v0 += __shfl_xor(v0, m, 64);
                v1 += __shfl_xor(v1, m, 64);
            }
            acc0[j] = v0; acc1[j] = v1;
        }
        if (lane == 0) {
            const float b0 = bias[oc0], b1 = bias[oc1];
            #pragma unroll
            for (int j = 0; j < 4; ++j) {
                const int il = ox*8 + oyh*4 + j;
                const float v0 = acc0[j] + b0;
                const float v1 = acc1[j] + b1;
                outp[oc0*64 + il] = 0.5f*v0*(1.0f + erff(v0*RSQRT2));
                outp[oc1*64 + il] = 0.5f*v1*(1.0f + erff(v1*RSQRT2));
            }
        }
        __syncthreads();
        if (t == 0) {
            __threadfence();
            __hip_atomic_fetch_add(cnt, 1u, __ATOMIC_RELEASE, __HIP_MEMORY_SCOPE_AGENT);
        }
    } else {
        // ---- spinner block: attention for image row x ----
        const int x = b - 256;
        float* vrow = patch;   // [ch][jl] pitch 65, 4160 floats
        // overlap with conv: reduce Vpart -> vrow (transposed)
        for (int idx = t; idx < 4096; idx += 256) {
            const int jl = idx >> 6, ch = idx & 63;
            float s = 0.f;
            #pragma unroll
            for (int yg = 0; yg < 8; ++yg)
                s += Vpart[(yg*64 + jl)*64 + ch];
            vrow[ch*65 + jl] = s;
        }
        __syncthreads();
        if (t == 0) {
            long it = 0;
            while (__hip_atomic_load(cnt, __ATOMIC_ACQUIRE, __HIP_MEMORY_SCOPE_AGENT) < 256u) {
                __builtin_amdgcn_s_sleep(2);
                if (++it > 200000000L) break;   // safety: never hang the harness
            }
        }
        __syncthreads();

        const int w4 = t >> 6, lane = t & 63;
        #pragma unroll
        for (int hh = 0; hh < 2; ++hh) {
            const int h = w4 + hh*4;
            float d = 0.f;
            #pragma unroll
            for (int c = 0; c < 8; ++c)
                d = fmaf(qd[(h*8 + c)*64 + x], kd[(h*8 + c)*64 + lane], d);
            d *= SCALE;
            float m = d;
            #pragma unroll
            for (int mm = 1; mm < 64; mm <<= 1) m = fmaxf(m, __shfl_xor(m, mm, 64));
            const float e = __expf(d - m);
            float ssum = e;
            #pragma unroll
            for (int mm = 1; mm < 64; mm <<= 1) ssum += __shfl_xor(ssum, mm, 64);
            const float p = e / ssum;
            #pragma unroll
            for (int c = 0; c < 8; ++c) {
                float r = p * vrow[(h*8 + c)*65 + lane];
                #pragma unroll
                for (int mm = 1; mm < 64; mm <<= 1) r += __shfl_xor(r, mm, 64);
                out[(h*8 + c)*4096 + x*64 + lane] = r;
            }
        }
    }
}

extern "C" void kernel_launch(void* const* d_in, const int* in_sizes, int n_in,
                              void* d_out, int out_size, void* d_ws, size_t ws_size,
                              hipStream_t stream) {
    const float* f     = (const float*)d_in[0];
    const float* w_qkv = (const float*)d_in[1];
    const float* wq    = (const float*)d_in[2];
    const float* bq    = (const float*)d_in[3];
    const float* wk    = (const float*)d_in[4];
    const float* bk    = (const float*)d_in[5];
    float* out = (float*)d_out;
    float* ws  = (float*)d_ws;

    k1<<<640, 192, 13120*4, stream>>>(f, w_qkv, wq, wk, ws);
    k2<<<320, 256, 0, stream>>>(ws + QT_OFF, ws + KT_OFF,
                                ws + WQT_OFF, ws + WKT_OFF,
                                bq, bk, ws + QD_OFF, ws + KD_OFF,
                                ws + VP_OFF, (unsigned*)(ws + CNT_OFF), out);
}

// Round 4
// 54.006 us; speedup vs baseline: 1.7221x; 1.7221x over previous
//
#include <hip/hip_runtime.h>

#define SCALE 0.35355339059327379f   // 8^-0.5
#define RSQRT2 0.70710678118654752f

// ws layout (float offsets)
#define QT_SZ   (68*68*64)           // padded transposed q image: [xp][yp][ic]
#define WT_SZ   (64*64*132)          // [oc][ic][kh][12] (11 used + 1 pad)
#define QT_OFF  0
#define KT_OFF  (QT_OFF + QT_SZ)
#define WQT_OFF (KT_OFF + QT_SZ)
#define WKT_OFF (WQT_OFF + WT_SZ)
#define QD_OFF  (WKT_OFF + WT_SZ)    // [oc][il] 64*64
#define KD_OFF  (QD_OFF + 4096)
#define VP_OFF  (KD_OFF + 4096)      // Vpart [yg][x][ch] 8*64*64
#define VR_OFF  (VP_OFF + 8*64*64)   // Vrow  [ch][jl] 64*64

// ---------------- K1: 1x1 conv (q,k -> transposed padded imgs; v -> row-mean partials)
//                  + weight transposes for K2 ----------------
__global__ __launch_bounds__(192) void k1(const float* __restrict__ f,
                                          const float* __restrict__ w_qkv,
                                          const float* __restrict__ wq,
                                          const float* __restrict__ wk,
                                          float* __restrict__ ws)
{
    extern __shared__ float sm[];
    const int b = blockIdx.x, t = threadIdx.x;
    if (b < 512) {
        // compute block: x row, yg = group of 8 y's
        const int x = b >> 3, yg = b & 7;
        const int w = t >> 6, lane = t & 63;   // wave w: 0=q,1=k,2=v ; lane = oc
        float* fl = sm;           // [64][12] f slab (8 y per ic, padded pitch 12)
        float* wt = sm + 768;     // [64 ic][193] transposed w_qkv (pitch 193)
        if (t < 128) {
            const int ic = t >> 1, part = t & 1;
            *(float4*)&fl[ic*12 + part*4] =
                *(const float4*)(f + ic*4096 + x*64 + yg*8 + part*4);
        }
        #pragma unroll
        for (int j = 0; j < 16; ++j) {
            const int idx = t + 192*j;          // float4 index in [0,3072)
            float4 v = *(const float4*)(w_qkv + 4*idx);
            const int oc = idx >> 4;            // (4*idx)/64
            const int ic0 = (4*idx) & 63;
            wt[(ic0+0)*193 + oc] = v.x;
            wt[(ic0+1)*193 + oc] = v.y;
            wt[(ic0+2)*193 + oc] = v.z;
            wt[(ic0+3)*193 + oc] = v.w;
        }
        __syncthreads();
        float acc[8] = {0.f,0.f,0.f,0.f,0.f,0.f,0.f,0.f};
        #pragma unroll 8
        for (int ic = 0; ic < 64; ++ic) {
            const float wv = wt[ic*193 + w*64 + lane];
            const float4 a = *(const float4*)&fl[ic*12];
            const float4 c = *(const float4*)&fl[ic*12 + 4];
            acc[0] = fmaf(wv, a.x, acc[0]);
            acc[1] = fmaf(wv, a.y, acc[1]);
            acc[2] = fmaf(wv, a.z, acc[2]);
            acc[3] = fmaf(wv, a.w, acc[3]);
            acc[4] = fmaf(wv, c.x, acc[4]);
            acc[5] = fmaf(wv, c.y, acc[5]);
            acc[6] = fmaf(wv, c.z, acc[6]);
            acc[7] = fmaf(wv, c.w, acc[7]);
        }
        if (w < 2) {
            float* img = (w == 0) ? (ws + QT_OFF) : (ws + KT_OFF);
            const int rowb = (x + 2) * 68;
            #pragma unroll
            for (int j = 0; j < 8; ++j)
                img[(rowb + yg*8 + j + 2)*64 + lane] = acc[j];
            if (yg == 0) { img[(rowb+0)*64+lane] = 0.f; img[(rowb+1)*64+lane] = 0.f; }
            if (yg == 7) { img[(rowb+66)*64+lane] = 0.f; img[(rowb+67)*64+lane] = 0.f; }
            if (x < 4) {  // zero pad rows xp in {0,1,66,67}; yg splits the 68 cols
                const int xp = (x < 2) ? x : 64 + x;
                for (int yp = yg*9; yp < yg*9 + 9; ++yp)
                    if (yp < 68) img[(xp*68 + yp)*64 + lane] = 0.f;
            }
        } else {
            const float s = acc[0]+acc[1]+acc[2]+acc[3]+acc[4]+acc[5]+acc[6]+acc[7];
            (ws + VP_OFF)[(yg*64 + x)*64 + lane] = s * 0.015625f;   // /64 row-mean partial
        }
    } else {
        // weight transpose blocks: wq/wk [oc][ic][kh][kw] -> [oc][ic][kh][12]
        const int b2 = b - 512;
        const int type = b2 >> 6, oc = b2 & 63;
        const float* wsrc = type ? wk : wq;
        float* wdst = type ? (ws + WKT_OFF) : (ws + WQT_OFF);
        float* wl = sm;   // 7744 floats, [ic][121]
        #pragma unroll
        for (int j = 0; j < 11; ++j) {
            const int idx = t + 192*j;
            if (idx < 1936)
                *(float4*)&wl[4*idx] = *(const float4*)(wsrc + oc*7744 + 4*idx);
        }
        __syncthreads();
        for (int p = t; p < 704; p += 192) {   // 64 ic x 11 kh
            const int ic = p / 11, kh = p % 11;
            const float* src = &wl[ic*121 + kh*11];
            float* dst = &wdst[(oc*64 + ic)*132 + kh*12];
            #pragma unroll
            for (int kw = 0; kw < 11; ++kw) dst[kw] = src[kw];
        }
    }
}

// ---------------- K2: 11x11 stride-8 pad-2 conv + bias + exact GELU (blocks 0..255)
//                  + independent Vpart->Vrow reduce blocks (256..319) ----------------
__global__ __launch_bounds__(256) void k2(const float* __restrict__ ws_qT,
                                          const float* __restrict__ ws_kT,
                                          const float* __restrict__ ws_wqT,
                                          const float* __restrict__ ws_wkT,
                                          const float* __restrict__ bq,
                                          const float* __restrict__ bk,
                                          float* __restrict__ qd,
                                          float* __restrict__ kd,
                                          const float* __restrict__ Vpart,
                                          float* __restrict__ Vrow)
{
    __shared__ float patch[64*223];   // [64 ic][pitch 223] (223 odd -> 2-way aliasing only)
    const int b = blockIdx.x;
    const int t = threadIdx.x;

    if (b >= 256) {
        // ---- Vrow reduce block: jl = b-256, lane = ch (coalesced loads) ----
        if (t < 64) {
            const int jl = b - 256;
            float s = 0.f;
            #pragma unroll
            for (int yg = 0; yg < 8; ++yg)
                s += Vpart[(yg*64 + jl)*64 + t];
            Vrow[t*64 + jl] = s;    // [ch][jl]
        }
        return;
    }

    const int type = b >> 7, ox = (b >> 4) & 7, ocg = (b >> 1) & 7, oyh = b & 1;
    const float* img  = type ? ws_kT : ws_qT;
    const float* wT   = type ? ws_wkT : ws_wqT;
    const float* bias = type ? bk : bq;
    float* outp = type ? kd : qd;
    const int ocp = t >> 6, lane = t & 63;

    const int oc0 = ocg*8 + ocp*2, oc1 = oc0 + 1;
    const float* w0b = wT + (oc0*64 + lane)*132;
    const float* w1b = wT + (oc1*64 + lane)*132;
    float acc0[4] = {0.f,0.f,0.f,0.f};
    float acc1[4] = {0.f,0.f,0.f,0.f};

#define KH_BODY(khl, khg)                                                        \
    {                                                                            \
        const float4 a0 = *(const float4*)(w0b + (khg)*12);                      \
        const float4 b0 = *(const float4*)(w0b + (khg)*12 + 4);                  \
        const float4 c0 = *(const float4*)(w0b + (khg)*12 + 8);                  \
        const float4 a1 = *(const float4*)(w1b + (khg)*12);                      \
        const float4 b1 = *(const float4*)(w1b + (khg)*12 + 4);                  \
        const float4 c1 = *(const float4*)(w1b + (khg)*12 + 8);                  \
        const float* prow = &patch[lane*223 + (khl)*37];                         \
        _Pragma("unroll")                                                        \
        for (int oy = 0; oy < 4; ++oy) {                                         \
            const float* pr = prow + oy*8;                                       \
            acc0[oy] = fmaf(a0.x, pr[0], acc0[oy]);                              \
            acc1[oy] = fmaf(a1.x, pr[0], acc1[oy]);                              \
            acc0[oy] = fmaf(a0.y, pr[1], acc0[oy]);                              \
            acc1[oy] = fmaf(a1.y, pr[1], acc1[oy]);                              \
            acc0[oy] = fmaf(a0.z, pr[2], acc0[oy]);                              \
            acc1[oy] = fmaf(a1.z, pr[2], acc1[oy]);                              \
            acc0[oy] = fmaf(a0.w, pr[3], acc0[oy]);                              \
            acc1[oy] = fmaf(a1.w, pr[3], acc1[oy]);                              \
            acc0[oy] = fmaf(b0.x, pr[4], acc0[oy]);                              \
            acc1[oy] = fmaf(b1.x, pr[4], acc1[oy]);                              \
            acc0[oy] = fmaf(b0.y, pr[5], acc0[oy]);                              \
            acc1[oy] = fmaf(b1.y, pr[5], acc1[oy]);                              \
            acc0[oy] = fmaf(b0.z, pr[6], acc0[oy]);                              \
            acc1[oy] = fmaf(b1.z, pr[6], acc1[oy]);                              \
            acc0[oy] = fmaf(b0.w, pr[7], acc0[oy]);                              \
            acc1[oy] = fmaf(b1.w, pr[7], acc1[oy]);                              \
            acc0[oy] = fmaf(c0.x, pr[8], acc0[oy]);                              \
            acc1[oy] = fmaf(c1.x, pr[8], acc1[oy]);                              \
            acc0[oy] = fmaf(c0.y, pr[9], acc0[oy]);                              \
            acc1[oy] = fmaf(c1.y, pr[9], acc1[oy]);                              \
            acc0[oy] = fmaf(c0.z, pr[10], acc0[oy]);                             \
            acc1[oy] = fmaf(c1.z, pr[10], acc1[oy]);                             \
        }                                                                        \
    }

    // ---- chunk 0: kh 0..5 ----
    for (int kh = 0; kh < 6; ++kh) {
        const int xrow = (ox*8 + kh) * 68;
        for (int yl = ocp; yl < 35; yl += 4)
            patch[lane*223 + kh*37 + yl] = img[(xrow + oyh*32 + yl)*64 + lane];
    }
    __syncthreads();
    #pragma unroll
    for (int kh = 0; kh < 6; ++kh) KH_BODY(kh, kh)
    __syncthreads();
    // ---- chunk 1: kh 6..10 ----
    for (int kh = 0; kh < 5; ++kh) {
        const int xrow = (ox*8 + 6 + kh) * 68;
        for (int yl = ocp; yl < 35; yl += 4)
            patch[lane*223 + kh*37 + yl] = img[(xrow + oyh*32 + yl)*64 + lane];
    }
    __syncthreads();
    #pragma unroll
    for (int kh = 0; kh < 5; ++kh) KH_BODY(kh, kh + 6)
#undef KH_BODY

    #pragma unroll
    for (int j = 0; j < 4; ++j) {
        float v0 = acc0[j], v1 = acc1[j];
        #pragma unroll
        for (int m = 1; m < 64; m <<= 1) {
            v0 += __shfl_xor(v0, m, 64);
            v1 += __shfl_xor(v1, m, 64);
        }
        acc0[j] = v0; acc1[j] = v1;
    }
    if (lane == 0) {
        const float b0 = bias[oc0], b1 = bias[oc1];
        #pragma unroll
        for (int j = 0; j < 4; ++j) {
            const int il = ox*8 + oyh*4 + j;
            const float v0 = acc0[j] + b0;
            const float v1 = acc1[j] + b1;
            outp[oc0*64 + il] = 0.5f*v0*(1.0f + erff(v0*RSQRT2));
            outp[oc1*64 + il] = 0.5f*v1*(1.0f + erff(v1*RSQRT2));
        }
    }
}

// ---------------- K3: dots + softmax + PV + broadcast store ----------------
// grid 64 (i = low-res query index), 512 threads: wave = head h, lane = jl.
__global__ __launch_bounds__(512) void k3(const float* __restrict__ qd,
                                          const float* __restrict__ kd,
                                          const float* __restrict__ Vrow,
                                          float* __restrict__ out)
{
    __shared__ float vrow[64*65];   // [ch][jl], pitch 65
    const int x = blockIdx.x, t = threadIdx.x;
    for (int idx = t; idx < 4096; idx += 512)
        vrow[(idx >> 6)*65 + (idx & 63)] = Vrow[idx];
    __syncthreads();
    const int h = t >> 6, lane = t & 63;
    float d = 0.f;
    #pragma unroll
    for (int c = 0; c < 8; ++c)
        d = fmaf(qd[(h*8 + c)*64 + x], kd[(h*8 + c)*64 + lane], d);
    d *= SCALE;
    float m = d;
    #pragma unroll
    for (int mm = 1; mm < 64; mm <<= 1) m = fmaxf(m, __shfl_xor(m, mm, 64));
    const float e = __expf(d - m);
    float ssum = e;
    #pragma unroll
    for (int mm = 1; mm < 64; mm <<= 1) ssum += __shfl_xor(ssum, mm, 64);
    const float p = e / ssum;
    #pragma unroll
    for (int c = 0; c < 8; ++c) {
        float r = p * vrow[(h*8 + c)*65 + lane];
        #pragma unroll
        for (int mm = 1; mm < 64; mm <<= 1) r += __shfl_xor(r, mm, 64);
        out[(h*8 + c)*4096 + x*64 + lane] = r;
    }
}

extern "C" void kernel_launch(void* const* d_in, const int* in_sizes, int n_in,
                              void* d_out, int out_size, void* d_ws, size_t ws_size,
                              hipStream_t stream) {
    const float* f     = (const float*)d_in[0];
    const float* w_qkv = (const float*)d_in[1];
    const float* wq    = (const float*)d_in[2];
    const float* bq    = (const float*)d_in[3];
    const float* wk    = (const float*)d_in[4];
    const float* bk    = (const float*)d_in[5];
    float* out = (float*)d_out;
    float* ws  = (float*)d_ws;

    k1<<<640, 192, 13120*4, stream>>>(f, w_qkv, wq, wk, ws);
    k2<<<320, 256, 0, stream>>>(ws + QT_OFF, ws + KT_OFF,
                                ws + WQT_OFF, ws + WKT_OFF,
                                bq, bk, ws + QD_OFF, ws + KD_OFF,
                                ws + VP_OFF, ws + VR_OFF);
    k3<<<64, 512, 0, stream>>>(ws + QD_OFF, ws + KD_OFF, ws + VR_OFF, out);
}